// Round 5
// baseline (381.620 us; speedup 1.0000x reference)
//
#include <hip/hip_runtime.h>
#include <hip/hip_bf16.h>
#include <math.h>

typedef __attribute__((ext_vector_type(8))) short short8;   // bf16x8 MFMA frag
typedef __attribute__((ext_vector_type(4))) float floatx4;  // f32x4 MFMA acc
typedef float __attribute__((ext_vector_type(4))) f32x4;

static __device__ __forceinline__ unsigned short f2bf(float x) {
    union { float f; unsigned u; } v; v.f = x;
    unsigned r = v.u + 0x7FFFu + ((v.u >> 16) & 1u);
    return (unsigned short)(r >> 16);
}
static __device__ __forceinline__ unsigned packbf2(float a, float b) {
    return (unsigned)f2bf(a) | ((unsigned)f2bf(b) << 16);
}

// ---------------- Kernel 1: QKV projections via MFMA ----------------
__global__ __launch_bounds__(256) void qkv_kernel(
    const float* __restrict__ feat,
    const float* __restrict__ Wq, const float* __restrict__ bq,
    const float* __restrict__ Wk, const float* __restrict__ bk,
    const float* __restrict__ Wv, const float* __restrict__ bv,
    unsigned short* __restrict__ Qt, unsigned short* __restrict__ Kt,
    unsigned short* __restrict__ Vb, int N)
{
    const int n0 = blockIdx.x * 64;
    const int oh = blockIdx.y;           // o-half (64 o's)
    const int b  = blockIdx.z;
    const int t = threadIdx.x;
    const int w = t >> 6, lane = t & 63, g = lane >> 4, q = lane & 15;

    __shared__ __align__(16) unsigned ft[64 * 64];   // [n][c2 swz]
    __shared__ __align__(16) unsigned wl[64 * 64];   // [o_loc][c2 swz]

    const float* fb = feat + (size_t)b * 128 * N + n0;
    {
        int n = lane;
        int swz = (n & 7) << 2;
#pragma unroll
        for (int iter = 0; iter < 16; ++iter) {
            int c2 = iter * 4 + w;
            float x0 = fb[(size_t)(2 * c2) * N + n];
            float x1 = fb[(size_t)(2 * c2 + 1) * N + n];
            ft[n * 64 + (c2 ^ swz)] = packbf2(x0, x1);
        }
    }
    __syncthreads();

    short8 af[4];
    {
        int nl = w * 16 + q;
        const unsigned* base = ft + nl * 64;
        int swz = (nl & 7) << 2;
#pragma unroll
        for (int cs = 0; cs < 4; ++cs)
            af[cs] = *(const short8*)(base + ((cs * 16 + g * 4) ^ swz));
    }

    for (int p = 0; p < 3; ++p) {
        const float* W    = p == 0 ? Wq : (p == 1 ? Wk : Wv);
        const float* bias = p == 0 ? bq : (p == 1 ? bk : bv);
        const float* Wsrc = W + (size_t)oh * 64 * 128;
        __syncthreads();
        {
            int c2 = lane;
#pragma unroll
            for (int iter = 0; iter < 16; ++iter) {
                int ol = iter * 4 + w;
                float2 v = *(const float2*)(Wsrc + ol * 128 + c2 * 2);
                wl[ol * 64 + (c2 ^ ((ol & 7) << 2))] = packbf2(v.x, v.y);
            }
        }
        __syncthreads();

#pragma unroll
        for (int ot = 0; ot < 4; ++ot) {
            short8 wf[4];
            {
                const unsigned* basep = wl + (ot * 16 + q) * 64;
                int swz = (q & 7) << 2;
#pragma unroll
                for (int cs = 0; cs < 4; ++cs)
                    wf[cs] = *(const short8*)(basep + ((cs * 16 + g * 4) ^ swz));
            }
            floatx4 acc = {0.f, 0.f, 0.f, 0.f};
            if (p < 2) {
#pragma unroll
                for (int cs = 0; cs < 4; ++cs)
                    acc = __builtin_amdgcn_mfma_f32_16x16x32_bf16(af[cs], wf[cs], acc, 0, 0, 0);
                int o = oh * 64 + ot * 16 + q;
                float bo = bias[o];
                unsigned short* T = (p == 0 ? Qt : Kt) + (size_t)b * N * 128;
#pragma unroll
                for (int rr = 0; rr < 4; ++rr) {
                    int n = n0 + w * 16 + g * 4 + rr;
                    T[(size_t)n * 128 + o] = f2bf(acc[rr] + bo);
                }
            } else {
#pragma unroll
                for (int cs = 0; cs < 4; ++cs)
                    acc = __builtin_amdgcn_mfma_f32_16x16x32_bf16(wf[cs], af[cs], acc, 0, 0, 0);
                int n = n0 + w * 16 + q;
#pragma unroll
                for (int rr = 0; rr < 4; ++rr) {
                    int o = oh * 64 + ot * 16 + g * 4 + rr;
                    Vb[((size_t)b * 128 + o) * N + n] = f2bf(acc[rr] + bias[o]);
                }
            }
        }
    }
}

// ---------------- Kernel 2: fused flash attention ----------------
// 256 blocks (1/CU), 1024 threads = 16 waves (4/SIMD). Each wave owns an N/16
// i-chunk of 32 o's; K + att register-prefetched one 32-i tile ahead.
#define PST 40
__global__ __launch_bounds__(1024, 4) void attn_kernel(
    const unsigned short* __restrict__ Qt, const unsigned short* __restrict__ Kt,
    const unsigned short* __restrict__ Vb, const float* __restrict__ att,
    float* __restrict__ msg, int N)
{
    const int b = blockIdx.y;
    const int obase = blockIdx.x * 32;
    const int t = threadIdx.x;
    const int w = t >> 6, lane = t & 63, g = lane >> 4, q = lane & 15;

    __shared__ __align__(16) unsigned short P_s[16][32 * PST];  // 40 KB
    __shared__ float comb_s[16][32 * 33];                       // 67.6 KB
    __shared__ float l_s[16][32];
    __shared__ float linv_s[32];

    const unsigned short* Qb  = Qt + (size_t)b * N * 128;
    const unsigned short* Kb  = Kt + (size_t)b * N * 128;
    const unsigned short* Vbp = Vb + (size_t)b * 128 * N;
    const float* arow0 = att + (size_t)b * N * N + (size_t)(obase + q) * N;
    const float* arow1 = arow0 + (size_t)16 * N;

    short8 qf[2][4];
#pragma unroll
    for (int ot = 0; ot < 2; ++ot)
#pragma unroll
        for (int cs = 0; cs < 4; ++cs)
            qf[ot][cs] = *(const short8*)(Qb + (size_t)(obase + 16 * ot + q) * 128 + cs * 32 + g * 8);

    floatx4 macc[8][2];
#pragma unroll
    for (int ct = 0; ct < 8; ++ct) {
        macc[ct][0] = (floatx4){0.f, 0.f, 0.f, 0.f};
        macc[ct][1] = (floatx4){0.f, 0.f, 0.f, 0.f};
    }
    float l0 = 0.f, l1 = 0.f;
    unsigned short* Pw = P_s[w];
    const float rsd = 0.08838834764831845f;

    const int chunk = N >> 4;            // 256
    const int ib0 = w * chunk;
    const int ntile = chunk >> 5;        // 8

    short8 kN[2][4];
    f32x4 aN[2][2];
#pragma unroll
    for (int h = 0; h < 2; ++h) {
        const unsigned short* kr = Kb + (size_t)(ib0 + h * 16 + q) * 128 + g * 8;
#pragma unroll
        for (int cs = 0; cs < 4; ++cs) kN[h][cs] = *(const short8*)(kr + cs * 32);
        aN[0][h] = __builtin_nontemporal_load((const f32x4*)(arow0 + ib0 + h * 16 + g * 4));
        aN[1][h] = __builtin_nontemporal_load((const f32x4*)(arow1 + ib0 + h * 16 + g * 4));
    }

    for (int it = 0; it < ntile; ++it) {
        const int ib = ib0 + it * 32;
        short8 kC[2][4];
        f32x4 aC[2][2];
#pragma unroll
        for (int h = 0; h < 2; ++h) {
#pragma unroll
            for (int cs = 0; cs < 4; ++cs) kC[h][cs] = kN[h][cs];
            aC[0][h] = aN[0][h]; aC[1][h] = aN[1][h];
        }
        if (it + 1 < ntile) {
            const int ibn = ib + 32;
#pragma unroll
            for (int h = 0; h < 2; ++h) {
                const unsigned short* kr = Kb + (size_t)(ibn + h * 16 + q) * 128 + g * 8;
#pragma unroll
                for (int cs = 0; cs < 4; ++cs) kN[h][cs] = *(const short8*)(kr + cs * 32);
                aN[0][h] = __builtin_nontemporal_load((const f32x4*)(arow0 + ibn + h * 16 + g * 4));
                aN[1][h] = __builtin_nontemporal_load((const f32x4*)(arow1 + ibn + h * 16 + g * 4));
            }
        }

#pragma unroll
        for (int h = 0; h < 2; ++h) {
            floatx4 s0 = {0.f,0.f,0.f,0.f}, s1 = {0.f,0.f,0.f,0.f};
#pragma unroll
            for (int cs = 0; cs < 4; ++cs) {
                s0 = __builtin_amdgcn_mfma_f32_16x16x32_bf16(kC[h][cs], qf[0][cs], s0, 0, 0, 0);
                s1 = __builtin_amdgcn_mfma_f32_16x16x32_bf16(kC[h][cs], qf[1][cs], s1, 0, 0, 0);
            }
            f32x4 a0 = aC[0][h], a1 = aC[1][h];
            float p00 = __expf(s0[0] * rsd * a0[0]);
            float p01 = __expf(s0[1] * rsd * a0[1]);
            float p02 = __expf(s0[2] * rsd * a0[2]);
            float p03 = __expf(s0[3] * rsd * a0[3]);
            float p10 = __expf(s1[0] * rsd * a1[0]);
            float p11 = __expf(s1[1] * rsd * a1[1]);
            float p12 = __expf(s1[2] * rsd * a1[2]);
            float p13 = __expf(s1[3] * rsd * a1[3]);
            l0 += (p00 + p01) + (p02 + p03);
            l1 += (p10 + p11) + (p12 + p13);
            *(uint2*)&Pw[q * PST + h * 16 + g * 4]        = make_uint2(packbf2(p00, p01), packbf2(p02, p03));
            *(uint2*)&Pw[(16 + q) * PST + h * 16 + g * 4] = make_uint2(packbf2(p10, p11), packbf2(p12, p13));
        }
        short8 pf0 = *(const short8*)&Pw[q * PST + g * 8];
        short8 pf1 = *(const short8*)&Pw[(16 + q) * PST + g * 8];
#pragma unroll
        for (int ct = 0; ct < 8; ++ct) {
            short8 vf = *(const short8*)(Vbp + (size_t)(ct * 16 + q) * N + ib + g * 8);
            macc[ct][0] = __builtin_amdgcn_mfma_f32_16x16x32_bf16(vf, pf0, macc[ct][0], 0, 0, 0);
            macc[ct][1] = __builtin_amdgcn_mfma_f32_16x16x32_bf16(vf, pf1, macc[ct][1], 0, 0, 0);
        }
    }

    // denominator: reduce 4 g-groups per o, then 16 waves
    l0 += __shfl_xor(l0, 16); l0 += __shfl_xor(l0, 32);
    l1 += __shfl_xor(l1, 16); l1 += __shfl_xor(l1, 32);
    if (lane < 16) { l_s[w][q] = l0; l_s[w][16 + q] = l1; }
    __syncthreads();
    if (t < 32) {
        float s = 0.f;
#pragma unroll
        for (int w2 = 0; w2 < 16; ++w2) s += l_s[w2][t];
        linv_s[t] = 1.f / s;
    }
    __syncthreads();

    // 16-way combine, 32 channels (2 ct) per phase
#pragma unroll
    for (int ct2 = 0; ct2 < 4; ++ct2) {
#pragma unroll
        for (int cc = 0; cc < 2; ++cc)
#pragma unroll
            for (int ot = 0; ot < 2; ++ot)
#pragma unroll
                for (int r = 0; r < 4; ++r)
                    comb_s[w][(cc * 16 + g * 4 + r) * 33 + 16 * ot + q] = macc[ct2 * 2 + cc][ot][r];
        __syncthreads();
        {
            int c = t >> 5, o = t & 31;   // c 0..31, o 0..31
            float s = 0.f;
#pragma unroll
            for (int w2 = 0; w2 < 16; ++w2) s += comb_s[w2][c * 33 + o];
            msg[(size_t)(b * 128 + ct2 * 32 + c) * N + obase + o] = s * linv_s[o];
        }
        __syncthreads();
    }
}

// ---------------- Kernel 3: fused MLP + residual ----------------
__global__ __launch_bounds__(256) void mlp_kernel(
    const float* __restrict__ msg, const float* __restrict__ feat,
    const float* __restrict__ W1, const float* __restrict__ b1,
    const float* __restrict__ g1, const float* __restrict__ be1,
    const float* __restrict__ m1, const float* __restrict__ v1,
    const float* __restrict__ W2, const float* __restrict__ b2,
    const float* __restrict__ g2, const float* __restrict__ be2,
    const float* __restrict__ m2, const float* __restrict__ v2,
    const float* __restrict__ W3, const float* __restrict__ b3,
    float* __restrict__ out, int N)
{
    const int b = blockIdx.y;
    const int nb = blockIdx.x * 32;
    const int t = threadIdx.x;
    const int n_l = t & 31, og = t >> 5;   // 8 groups
    const float EPS = 1e-5f;

    __shared__ float h1_s[64][32];
    __shared__ float h2_s[64][32];

    const float* msgb = msg + (size_t)b * 128 * N + nb;

    float acc[8];
#pragma unroll
    for (int i = 0; i < 8; ++i) acc[i] = 0.f;
    for (int c4 = 0; c4 < 128; c4 += 4) {
        float f0 = msgb[(size_t)(c4 + 0) * N + n_l];
        float f1 = msgb[(size_t)(c4 + 1) * N + n_l];
        float f2 = msgb[(size_t)(c4 + 2) * N + n_l];
        float f3 = msgb[(size_t)(c4 + 3) * N + n_l];
#pragma unroll
        for (int oi = 0; oi < 8; ++oi) {
            float4 wv = *(const float4*)(W1 + (og * 8 + oi) * 128 + c4);
            acc[oi] += wv.x * f0 + wv.y * f1 + wv.z * f2 + wv.w * f3;
        }
    }
#pragma unroll
    for (int oi = 0; oi < 8; ++oi) {
        int o = og * 8 + oi;
        float inv = g1[o] / sqrtf(v1[o] + EPS);
        float val = (acc[oi] + b1[o]) * inv + (be1[o] - m1[o] * inv);
        h1_s[o][n_l] = fmaxf(val, 0.f);
    }
    __syncthreads();

    float acc2[8];
#pragma unroll
    for (int i = 0; i < 8; ++i) acc2[i] = 0.f;
    for (int c4 = 0; c4 < 64; c4 += 4) {
        float f0 = h1_s[c4 + 0][n_l], f1 = h1_s[c4 + 1][n_l];
        float f2 = h1_s[c4 + 2][n_l], f3 = h1_s[c4 + 3][n_l];
#pragma unroll
        for (int oi = 0; oi < 8; ++oi) {
            float4 wv = *(const float4*)(W2 + (og * 8 + oi) * 64 + c4);
            acc2[oi] += wv.x * f0 + wv.y * f1 + wv.z * f2 + wv.w * f3;
        }
    }
#pragma unroll
    for (int oi = 0; oi < 8; ++oi) {
        int o = og * 8 + oi;
        float inv = g2[o] / sqrtf(v2[o] + EPS);
        float val = (acc2[oi] + b2[o]) * inv + (be2[o] - m2[o] * inv);
        h2_s[o][n_l] = fmaxf(val, 0.f);
    }
    __syncthreads();

    float acc3[16];
#pragma unroll
    for (int i = 0; i < 16; ++i) acc3[i] = 0.f;
    for (int c4 = 0; c4 < 64; c4 += 4) {
        float f0 = h2_s[c4 + 0][n_l], f1 = h2_s[c4 + 1][n_l];
        float f2 = h2_s[c4 + 2][n_l], f3 = h2_s[c4 + 3][n_l];
#pragma unroll
        for (int oi = 0; oi < 16; ++oi) {
            float4 wv = *(const float4*)(W3 + (og * 16 + oi) * 64 + c4);
            acc3[oi] += wv.x * f0 + wv.y * f1 + wv.z * f2 + wv.w * f3;
        }
    }
#pragma unroll
    for (int oi = 0; oi < 16; ++oi) {
        int o = og * 16 + oi;
        size_t idx = (size_t)(b * 128 + o) * N + nb + n_l;
        out[idx] = feat[idx] + acc3[oi] + b3[o];
    }
}

extern "C" void kernel_launch(void* const* d_in, const int* in_sizes, int n_in,
                              void* d_out, int out_size, void* d_ws, size_t ws_size,
                              hipStream_t stream)
{
    const float* feat = (const float*)d_in[0];
    const float* att  = (const float*)d_in[1];
    const float* Wq = (const float*)d_in[2];  const float* bq = (const float*)d_in[3];
    const float* Wk = (const float*)d_in[4];  const float* bk = (const float*)d_in[5];
    const float* Wv = (const float*)d_in[6];  const float* bv = (const float*)d_in[7];
    const float* W1 = (const float*)d_in[8];  const float* b1 = (const float*)d_in[9];
    const float* g1 = (const float*)d_in[10]; const float* be1 = (const float*)d_in[11];
    const float* m1 = (const float*)d_in[12]; const float* v1 = (const float*)d_in[13];
    const float* W2 = (const float*)d_in[14]; const float* b2 = (const float*)d_in[15];
    const float* g2 = (const float*)d_in[16]; const float* be2 = (const float*)d_in[17];
    const float* m2 = (const float*)d_in[18]; const float* v2 = (const float*)d_in[19];
    const float* W3 = (const float*)d_in[20]; const float* b3 = (const float*)d_in[21];

    long long bsN = (long long)in_sizes[0] / 128;   // bs*N
    long long NN  = (long long)in_sizes[1];         // bs*N*N
    int N  = (int)(NN / bsN);
    int bs = (int)(bsN / N);

    char* ws = (char*)d_ws;
    unsigned short* Qt = (unsigned short*)ws;            // bs*N*128 bf16
    unsigned short* Kt = Qt + (size_t)bs * N * 128;      // bs*N*128 bf16
    unsigned short* Vb = Kt + (size_t)bs * N * 128;      // bs*128*N bf16
    float* msg = (float*)(Vb + (size_t)bs * N * 128);    // bs*128*N f32

    dim3 grid1(N / 64, 2, bs);
    qkv_kernel<<<grid1, 256, 0, stream>>>(feat, Wq, bq, Wk, bk, Wv, bv, Qt, Kt, Vb, N);

    dim3 grid2(N / 32, bs);
    attn_kernel<<<grid2, 1024, 0, stream>>>(Qt, Kt, Vb, att, msg, N);

    dim3 grid3(N / 32, bs);
    mlp_kernel<<<grid3, 256, 0, stream>>>(msg, feat,
        W1, b1, g1, be1, m1, v1, W2, b2, g2, be2, m2, v2, W3, b3,
        (float*)d_out, N);
}

// Round 6
// 188.984 us; speedup vs baseline: 2.0193x; 2.0193x over previous
//
#include <hip/hip_runtime.h>
#include <hip/hip_bf16.h>
#include <math.h>

typedef __attribute__((ext_vector_type(8))) short short8;   // bf16x8 MFMA frag
typedef __attribute__((ext_vector_type(4))) float floatx4;  // f32x4 MFMA acc
typedef float __attribute__((ext_vector_type(4))) f32x4;

static __device__ __forceinline__ unsigned short f2bf(float x) {
    union { float f; unsigned u; } v; v.f = x;
    unsigned r = v.u + 0x7FFFu + ((v.u >> 16) & 1u);
    return (unsigned short)(r >> 16);
}
static __device__ __forceinline__ unsigned packbf2(float a, float b) {
    return (unsigned)f2bf(a) | ((unsigned)f2bf(b) << 16);
}

// ---------------- Kernel 1: QKV projections via MFMA ----------------
__global__ __launch_bounds__(256) void qkv_kernel(
    const float* __restrict__ feat,
    const float* __restrict__ Wq, const float* __restrict__ bq,
    const float* __restrict__ Wk, const float* __restrict__ bk,
    const float* __restrict__ Wv, const float* __restrict__ bv,
    unsigned short* __restrict__ Qt, unsigned short* __restrict__ Kt,
    unsigned short* __restrict__ Vb, int N)
{
    const int n0 = blockIdx.x * 64;
    const int oh = blockIdx.y;           // o-half (64 o's)
    const int b  = blockIdx.z;
    const int t = threadIdx.x;
    const int w = t >> 6, lane = t & 63, g = lane >> 4, q = lane & 15;

    __shared__ __align__(16) unsigned ft[64 * 64];   // [n][c2 swz]
    __shared__ __align__(16) unsigned wl[64 * 64];   // [o_loc][c2 swz]

    const float* fb = feat + (size_t)b * 128 * N + n0;
    {
        int n = lane;
        int swz = (n & 7) << 2;
#pragma unroll
        for (int iter = 0; iter < 16; ++iter) {
            int c2 = iter * 4 + w;
            float x0 = fb[(size_t)(2 * c2) * N + n];
            float x1 = fb[(size_t)(2 * c2 + 1) * N + n];
            ft[n * 64 + (c2 ^ swz)] = packbf2(x0, x1);
        }
    }
    __syncthreads();

    short8 af[4];
    {
        int nl = w * 16 + q;
        const unsigned* base = ft + nl * 64;
        int swz = (nl & 7) << 2;
#pragma unroll
        for (int cs = 0; cs < 4; ++cs)
            af[cs] = *(const short8*)(base + ((cs * 16 + g * 4) ^ swz));
    }

    for (int p = 0; p < 3; ++p) {
        const float* W    = p == 0 ? Wq : (p == 1 ? Wk : Wv);
        const float* bias = p == 0 ? bq : (p == 1 ? bk : bv);
        const float* Wsrc = W + (size_t)oh * 64 * 128;
        __syncthreads();
        {
            int c2 = lane;
#pragma unroll
            for (int iter = 0; iter < 16; ++iter) {
                int ol = iter * 4 + w;
                float2 v = *(const float2*)(Wsrc + ol * 128 + c2 * 2);
                wl[ol * 64 + (c2 ^ ((ol & 7) << 2))] = packbf2(v.x, v.y);
            }
        }
        __syncthreads();

#pragma unroll
        for (int ot = 0; ot < 4; ++ot) {
            short8 wf[4];
            {
                const unsigned* basep = wl + (ot * 16 + q) * 64;
                int swz = (q & 7) << 2;
#pragma unroll
                for (int cs = 0; cs < 4; ++cs)
                    wf[cs] = *(const short8*)(basep + ((cs * 16 + g * 4) ^ swz));
            }
            floatx4 acc = {0.f, 0.f, 0.f, 0.f};
            if (p < 2) {
#pragma unroll
                for (int cs = 0; cs < 4; ++cs)
                    acc = __builtin_amdgcn_mfma_f32_16x16x32_bf16(af[cs], wf[cs], acc, 0, 0, 0);
                int o = oh * 64 + ot * 16 + q;
                float bo = bias[o];
                unsigned short* T = (p == 0 ? Qt : Kt) + (size_t)b * N * 128;
#pragma unroll
                for (int rr = 0; rr < 4; ++rr) {
                    int n = n0 + w * 16 + g * 4 + rr;
                    T[(size_t)n * 128 + o] = f2bf(acc[rr] + bo);
                }
            } else {
#pragma unroll
                for (int cs = 0; cs < 4; ++cs)
                    acc = __builtin_amdgcn_mfma_f32_16x16x32_bf16(wf[cs], af[cs], acc, 0, 0, 0);
                int n = n0 + w * 16 + q;
#pragma unroll
                for (int rr = 0; rr < 4; ++rr) {
                    int o = oh * 64 + ot * 16 + g * 4 + rr;
                    Vb[((size_t)b * 128 + o) * N + n] = f2bf(acc[rr] + bias[o]);
                }
            }
        }
    }
}

// ---------------- Kernel 2: fused flash attention ----------------
// 512 blocks (2/CU), 512 threads. Block = 16 o's; each of 8 waves owns an
// N/8 i-chunk. K + att register-prefetched depth 1; no-max softmax.
// Register budget tuned for 4 waves/SIMD (cap 128): macc 32 + qf 16 + kN 32.
#define PST 40
__global__ __launch_bounds__(512, 4) void attn_kernel(
    const unsigned short* __restrict__ Qt, const unsigned short* __restrict__ Kt,
    const unsigned short* __restrict__ Vb, const float* __restrict__ att,
    float* __restrict__ msg, int N)
{
    const int b = blockIdx.y;
    const int obase = blockIdx.x * 16;
    const int t = threadIdx.x;
    const int w = t >> 6, lane = t & 63, g = lane >> 4, q = lane & 15;

    __shared__ __align__(16) unsigned short P_s[8][16 * PST];  // 10 KB
    __shared__ float comb_s[8][32 * 17];                        // 17.4 KB
    __shared__ float l_s[8][16];
    __shared__ float linv_s[16];

    const unsigned short* Qb  = Qt + (size_t)b * N * 128;
    const unsigned short* Kb  = Kt + (size_t)b * N * 128;
    const unsigned short* Vbp = Vb + (size_t)b * 128 * N;
    const float* arow = att + (size_t)b * N * N + (size_t)(obase + q) * N;

    short8 qf[4];
#pragma unroll
    for (int cs = 0; cs < 4; ++cs)
        qf[cs] = *(const short8*)(Qb + (size_t)(obase + q) * 128 + cs * 32 + g * 8);

    floatx4 macc[8];
#pragma unroll
    for (int ct = 0; ct < 8; ++ct) macc[ct] = (floatx4){0.f, 0.f, 0.f, 0.f};
    float l0 = 0.f;
    unsigned short* Pw = P_s[w];
    const float rsd = 0.08838834764831845f;

    const int chunk = N >> 3;            // 512
    const int ib0 = w * chunk;
    const int ntile = chunk >> 5;        // 16

    short8 kN[2][4];
    f32x4 aN[2];
#pragma unroll
    for (int h = 0; h < 2; ++h) {
        const unsigned short* kr = Kb + (size_t)(ib0 + h * 16 + q) * 128 + g * 8;
#pragma unroll
        for (int cs = 0; cs < 4; ++cs) kN[h][cs] = *(const short8*)(kr + cs * 32);
        aN[h] = __builtin_nontemporal_load((const f32x4*)(arow + ib0 + h * 16 + g * 4));
    }

    for (int it = 0; it < ntile; ++it) {
        const int ib = ib0 + it * 32;
        // 1. QK MFMAs consume kN (loaded last tile) directly
        floatx4 s0 = {0.f,0.f,0.f,0.f}, s1 = {0.f,0.f,0.f,0.f};
#pragma unroll
        for (int cs = 0; cs < 4; ++cs) {
            s0 = __builtin_amdgcn_mfma_f32_16x16x32_bf16(kN[0][cs], qf[cs], s0, 0, 0, 0);
            s1 = __builtin_amdgcn_mfma_f32_16x16x32_bf16(kN[1][cs], qf[cs], s1, 0, 0, 0);
        }
        // 2. copy att regs, then refill prefetches for next tile
        f32x4 av0 = aN[0], av1 = aN[1];
        if (it + 1 < ntile) {
            const int ibn = ib + 32;
#pragma unroll
            for (int h = 0; h < 2; ++h) {
                const unsigned short* kr = Kb + (size_t)(ibn + h * 16 + q) * 128 + g * 8;
#pragma unroll
                for (int cs = 0; cs < 4; ++cs) kN[h][cs] = *(const short8*)(kr + cs * 32);
                aN[h] = __builtin_nontemporal_load((const f32x4*)(arow + ibn + h * 16 + g * 4));
            }
        }
        // 3-4. softmax numerator + P strip
        {
            float p0 = __expf(s0[0] * rsd * av0[0]);
            float p1 = __expf(s0[1] * rsd * av0[1]);
            float p2 = __expf(s0[2] * rsd * av0[2]);
            float p3 = __expf(s0[3] * rsd * av0[3]);
            float p4 = __expf(s1[0] * rsd * av1[0]);
            float p5 = __expf(s1[1] * rsd * av1[1]);
            float p6 = __expf(s1[2] * rsd * av1[2]);
            float p7 = __expf(s1[3] * rsd * av1[3]);
            l0 += ((p0 + p1) + (p2 + p3)) + ((p4 + p5) + (p6 + p7));
            *(uint2*)&Pw[q * PST + g * 4]      = make_uint2(packbf2(p0, p1), packbf2(p2, p3));
            *(uint2*)&Pw[q * PST + 16 + g * 4] = make_uint2(packbf2(p4, p5), packbf2(p6, p7));
        }
        // 5-6. PV over this 32-i tile
        short8 pf = *(const short8*)&Pw[q * PST + g * 8];
#pragma unroll
        for (int ct = 0; ct < 8; ++ct) {
            short8 vf = *(const short8*)(Vbp + (size_t)(ct * 16 + q) * N + ib + g * 8);
            macc[ct] = __builtin_amdgcn_mfma_f32_16x16x32_bf16(vf, pf, macc[ct], 0, 0, 0);
        }
    }

    // denominator
    l0 += __shfl_xor(l0, 16); l0 += __shfl_xor(l0, 32);
    if (lane < 16) l_s[w][q] = l0;
    __syncthreads();
    if (t < 16) {
        float s = 0.f;
#pragma unroll
        for (int w2 = 0; w2 < 8; ++w2) s += l_s[w2][t];
        linv_s[t] = 1.f / s;
    }
    __syncthreads();

    // 8-way combine, 32 channels (2 ct) per phase
#pragma unroll
    for (int ct2 = 0; ct2 < 4; ++ct2) {
#pragma unroll
        for (int cc = 0; cc < 2; ++cc)
#pragma unroll
            for (int r = 0; r < 4; ++r)
                comb_s[w][(cc * 16 + g * 4 + r) * 17 + q] = macc[ct2 * 2 + cc][r];
        __syncthreads();
        {
            int c = t >> 4, o = t & 15;   // c 0..31, o 0..15
            float s = 0.f;
#pragma unroll
            for (int w2 = 0; w2 < 8; ++w2) s += comb_s[w2][c * 17 + o];
            msg[(size_t)(b * 128 + ct2 * 32 + c) * N + obase + o] = s * linv_s[o];
        }
        __syncthreads();
    }
}

// ---------------- Kernel 3: fused MLP + residual ----------------
__global__ __launch_bounds__(256) void mlp_kernel(
    const float* __restrict__ msg, const float* __restrict__ feat,
    const float* __restrict__ W1, const float* __restrict__ b1,
    const float* __restrict__ g1, const float* __restrict__ be1,
    const float* __restrict__ m1, const float* __restrict__ v1,
    const float* __restrict__ W2, const float* __restrict__ b2,
    const float* __restrict__ g2, const float* __restrict__ be2,
    const float* __restrict__ m2, const float* __restrict__ v2,
    const float* __restrict__ W3, const float* __restrict__ b3,
    float* __restrict__ out, int N)
{
    const int b = blockIdx.y;
    const int nb = blockIdx.x * 32;
    const int t = threadIdx.x;
    const int n_l = t & 31, og = t >> 5;   // 8 groups
    const float EPS = 1e-5f;

    __shared__ float h1_s[64][32];
    __shared__ float h2_s[64][32];

    const float* msgb = msg + (size_t)b * 128 * N + nb;

    float acc[8];
#pragma unroll
    for (int i = 0; i < 8; ++i) acc[i] = 0.f;
    for (int c4 = 0; c4 < 128; c4 += 4) {
        float f0 = msgb[(size_t)(c4 + 0) * N + n_l];
        float f1 = msgb[(size_t)(c4 + 1) * N + n_l];
        float f2 = msgb[(size_t)(c4 + 2) * N + n_l];
        float f3 = msgb[(size_t)(c4 + 3) * N + n_l];
#pragma unroll
        for (int oi = 0; oi < 8; ++oi) {
            float4 wv = *(const float4*)(W1 + (og * 8 + oi) * 128 + c4);
            acc[oi] += wv.x * f0 + wv.y * f1 + wv.z * f2 + wv.w * f3;
        }
    }
#pragma unroll
    for (int oi = 0; oi < 8; ++oi) {
        int o = og * 8 + oi;
        float inv = g1[o] / sqrtf(v1[o] + EPS);
        float val = (acc[oi] + b1[o]) * inv + (be1[o] - m1[o] * inv);
        h1_s[o][n_l] = fmaxf(val, 0.f);
    }
    __syncthreads();

    float acc2[8];
#pragma unroll
    for (int i = 0; i < 8; ++i) acc2[i] = 0.f;
    for (int c4 = 0; c4 < 64; c4 += 4) {
        float f0 = h1_s[c4 + 0][n_l], f1 = h1_s[c4 + 1][n_l];
        float f2 = h1_s[c4 + 2][n_l], f3 = h1_s[c4 + 3][n_l];
#pragma unroll
        for (int oi = 0; oi < 8; ++oi) {
            float4 wv = *(const float4*)(W2 + (og * 8 + oi) * 64 + c4);
            acc2[oi] += wv.x * f0 + wv.y * f1 + wv.z * f2 + wv.w * f3;
        }
    }
#pragma unroll
    for (int oi = 0; oi < 8; ++oi) {
        int o = og * 8 + oi;
        float inv = g2[o] / sqrtf(v2[o] + EPS);
        float val = (acc2[oi] + b2[o]) * inv + (be2[o] - m2[o] * inv);
        h2_s[o][n_l] = fmaxf(val, 0.f);
    }
    __syncthreads();

    float acc3[16];
#pragma unroll
    for (int i = 0; i < 16; ++i) acc3[i] = 0.f;
    for (int c4 = 0; c4 < 64; c4 += 4) {
        float f0 = h2_s[c4 + 0][n_l], f1 = h2_s[c4 + 1][n_l];
        float f2 = h2_s[c4 + 2][n_l], f3 = h2_s[c4 + 3][n_l];
#pragma unroll
        for (int oi = 0; oi < 16; ++oi) {
            float4 wv = *(const float4*)(W3 + (og * 16 + oi) * 64 + c4);
            acc3[oi] += wv.x * f0 + wv.y * f1 + wv.z * f2 + wv.w * f3;
        }
    }
#pragma unroll
    for (int oi = 0; oi < 16; ++oi) {
        int o = og * 16 + oi;
        size_t idx = (size_t)(b * 128 + o) * N + nb + n_l;
        out[idx] = feat[idx] + acc3[oi] + b3[o];
    }
}

extern "C" void kernel_launch(void* const* d_in, const int* in_sizes, int n_in,
                              void* d_out, int out_size, void* d_ws, size_t ws_size,
                              hipStream_t stream)
{
    const float* feat = (const float*)d_in[0];
    const float* att  = (const float*)d_in[1];
    const float* Wq = (const float*)d_in[2];  const float* bq = (const float*)d_in[3];
    const float* Wk = (const float*)d_in[4];  const float* bk = (const float*)d_in[5];
    const float* Wv = (const float*)d_in[6];  const float* bv = (const float*)d_in[7];
    const float* W1 = (const float*)d_in[8];  const float* b1 = (const float*)d_in[9];
    const float* g1 = (const float*)d_in[10]; const float* be1 = (const float*)d_in[11];
    const float* m1 = (const float*)d_in[12]; const float* v1 = (const float*)d_in[13];
    const float* W2 = (const float*)d_in[14]; const float* b2 = (const float*)d_in[15];
    const float* g2 = (const float*)d_in[16]; const float* be2 = (const float*)d_in[17];
    const float* m2 = (const float*)d_in[18]; const float* v2 = (const float*)d_in[19];
    const float* W3 = (const float*)d_in[20]; const float* b3 = (const float*)d_in[21];

    long long bsN = (long long)in_sizes[0] / 128;   // bs*N
    long long NN  = (long long)in_sizes[1];         // bs*N*N
    int N  = (int)(NN / bsN);
    int bs = (int)(bsN / N);

    char* ws = (char*)d_ws;
    unsigned short* Qt = (unsigned short*)ws;            // bs*N*128 bf16
    unsigned short* Kt = Qt + (size_t)bs * N * 128;      // bs*N*128 bf16
    unsigned short* Vb = Kt + (size_t)bs * N * 128;      // bs*128*N bf16
    float* msg = (float*)(Vb + (size_t)bs * N * 128);    // bs*128*N f32

    dim3 grid1(N / 64, 2, bs);
    qkv_kernel<<<grid1, 256, 0, stream>>>(feat, Wq, bq, Wk, bk, Wv, bv, Qt, Kt, Vb, N);

    dim3 grid2(N / 16, bs);
    attn_kernel<<<grid2, 512, 0, stream>>>(Qt, Kt, Vb, att, msg, N);

    dim3 grid3(N / 32, bs);
    mlp_kernel<<<grid3, 256, 0, stream>>>(msg, feat,
        W1, b1, g1, be1, m1, v1, W2, b2, g2, be2, m2, v2, W3, b3,
        (float*)d_out, N);
}

// Round 7
// 130.294 us; speedup vs baseline: 2.9289x; 1.4504x over previous
//
#include <hip/hip_runtime.h>
#include <hip/hip_bf16.h>
#include <math.h>

typedef __attribute__((ext_vector_type(8))) short short8;   // bf16x8 MFMA frag
typedef __attribute__((ext_vector_type(4))) float floatx4;  // f32x4 MFMA acc
typedef float __attribute__((ext_vector_type(4))) f32x4;

static __device__ __forceinline__ unsigned short f2bf(float x) {
    union { float f; unsigned u; } v; v.f = x;
    unsigned r = v.u + 0x7FFFu + ((v.u >> 16) & 1u);
    return (unsigned short)(r >> 16);
}
static __device__ __forceinline__ unsigned packbf2(float a, float b) {
    return (unsigned)f2bf(a) | ((unsigned)f2bf(b) << 16);
}

// ---------------- Kernel 1: QKV projections via MFMA ----------------
__global__ __launch_bounds__(256) void qkv_kernel(
    const float* __restrict__ feat,
    const float* __restrict__ Wq, const float* __restrict__ bq,
    const float* __restrict__ Wk, const float* __restrict__ bk,
    const float* __restrict__ Wv, const float* __restrict__ bv,
    unsigned short* __restrict__ Qt, unsigned short* __restrict__ Kt,
    unsigned short* __restrict__ Vb, int N)
{
    const int n0 = blockIdx.x * 64;
    const int oh = blockIdx.y;           // o-half (64 o's)
    const int b  = blockIdx.z;
    const int t = threadIdx.x;
    const int w = t >> 6, lane = t & 63, g = lane >> 4, q = lane & 15;

    __shared__ __align__(16) unsigned ft[64 * 64];   // [n][c2 swz]
    __shared__ __align__(16) unsigned wl[64 * 64];   // [o_loc][c2 swz]

    const float* fb = feat + (size_t)b * 128 * N + n0;
    {
        int n = lane;
        int swz = (n & 7) << 2;
#pragma unroll
        for (int iter = 0; iter < 16; ++iter) {
            int c2 = iter * 4 + w;
            float x0 = fb[(size_t)(2 * c2) * N + n];
            float x1 = fb[(size_t)(2 * c2 + 1) * N + n];
            ft[n * 64 + (c2 ^ swz)] = packbf2(x0, x1);
        }
    }
    __syncthreads();

    short8 af[4];
    {
        int nl = w * 16 + q;
        const unsigned* base = ft + nl * 64;
        int swz = (nl & 7) << 2;
#pragma unroll
        for (int cs = 0; cs < 4; ++cs)
            af[cs] = *(const short8*)(base + ((cs * 16 + g * 4) ^ swz));
    }

    for (int p = 0; p < 3; ++p) {
        const float* W    = p == 0 ? Wq : (p == 1 ? Wk : Wv);
        const float* bias = p == 0 ? bq : (p == 1 ? bk : bv);
        const float* Wsrc = W + (size_t)oh * 64 * 128;
        __syncthreads();
        {
            int c2 = lane;
#pragma unroll
            for (int iter = 0; iter < 16; ++iter) {
                int ol = iter * 4 + w;
                float2 v = *(const float2*)(Wsrc + ol * 128 + c2 * 2);
                wl[ol * 64 + (c2 ^ ((ol & 7) << 2))] = packbf2(v.x, v.y);
            }
        }
        __syncthreads();

#pragma unroll
        for (int ot = 0; ot < 4; ++ot) {
            short8 wf[4];
            {
                const unsigned* basep = wl + (ot * 16 + q) * 64;
                int swz = (q & 7) << 2;
#pragma unroll
                for (int cs = 0; cs < 4; ++cs)
                    wf[cs] = *(const short8*)(basep + ((cs * 16 + g * 4) ^ swz));
            }
            floatx4 acc = {0.f, 0.f, 0.f, 0.f};
            if (p < 2) {
#pragma unroll
                for (int cs = 0; cs < 4; ++cs)
                    acc = __builtin_amdgcn_mfma_f32_16x16x32_bf16(af[cs], wf[cs], acc, 0, 0, 0);
                int o = oh * 64 + ot * 16 + q;
                float bo = bias[o];
                unsigned short* T = (p == 0 ? Qt : Kt) + (size_t)b * N * 128;
#pragma unroll
                for (int rr = 0; rr < 4; ++rr) {
                    int n = n0 + w * 16 + g * 4 + rr;
                    T[(size_t)n * 128 + o] = f2bf(acc[rr] + bo);
                }
            } else {
#pragma unroll
                for (int cs = 0; cs < 4; ++cs)
                    acc = __builtin_amdgcn_mfma_f32_16x16x32_bf16(wf[cs], af[cs], acc, 0, 0, 0);
                int n = n0 + w * 16 + q;
#pragma unroll
                for (int rr = 0; rr < 4; ++rr) {
                    int o = oh * 64 + ot * 16 + g * 4 + rr;
                    Vb[((size_t)b * 128 + o) * N + n] = f2bf(acc[rr] + bias[o]);
                }
            }
        }
    }
}

// ---------------- Kernel 2: fused flash attention, split-i partials ----------------
// EXACT round-3 loop body/codegen (lb(512,2) -> VGPR ~120, no spill), grid
// doubled via split-i: 512 blocks (2/CU), partial (acc,l) merged in mlp.
#define PST 40
__global__ __launch_bounds__(512, 2) void attn_kernel(
    const unsigned short* __restrict__ Qt, const unsigned short* __restrict__ Kt,
    const unsigned short* __restrict__ Vb, const float* __restrict__ att,
    float* __restrict__ pmsg, float* __restrict__ pl, int N, int bs)
{
    const int b = blockIdx.z;
    const int split = blockIdx.y;
    const int obase = blockIdx.x * 32;
    const int t = threadIdx.x;
    const int w = t >> 6, lane = t & 63, g = lane >> 4, q = lane & 15;

    __shared__ __align__(16) unsigned short P_s[8][32 * PST];  // 20.5 KB
    __shared__ float comb_s[8][16 * 33];                        // 16.9 KB
    __shared__ float l_s[8][32];

    const unsigned short* Qb  = Qt + (size_t)b * N * 128;
    const unsigned short* Kb  = Kt + (size_t)b * N * 128;
    const unsigned short* Vbp = Vb + (size_t)b * 128 * N;
    const float* arow0 = att + (size_t)b * N * N + (size_t)(obase + q) * N;
    const float* arow1 = arow0 + (size_t)16 * N;

    short8 qf[2][4];
#pragma unroll
    for (int ot = 0; ot < 2; ++ot)
#pragma unroll
        for (int cs = 0; cs < 4; ++cs)
            qf[ot][cs] = *(const short8*)(Qb + (size_t)(obase + 16 * ot + q) * 128 + cs * 32 + g * 8);

    floatx4 macc[8][2];
#pragma unroll
    for (int ct = 0; ct < 8; ++ct) {
        macc[ct][0] = (floatx4){0.f, 0.f, 0.f, 0.f};
        macc[ct][1] = (floatx4){0.f, 0.f, 0.f, 0.f};
    }
    float l0 = 0.f, l1 = 0.f;
    unsigned short* Pw = P_s[w];
    const float rsd = 0.08838834764831845f;

    const int chunk = N >> 4;                        // 256
    const int ib0 = split * (N >> 1) + w * chunk;
    const int ntile = chunk >> 5;                    // 8

    short8 kN[2][4];
    f32x4 aN[2][2];
#pragma unroll
    for (int h = 0; h < 2; ++h) {
        const unsigned short* kr = Kb + (size_t)(ib0 + h * 16 + q) * 128 + g * 8;
#pragma unroll
        for (int cs = 0; cs < 4; ++cs) kN[h][cs] = *(const short8*)(kr + cs * 32);
        aN[0][h] = __builtin_nontemporal_load((const f32x4*)(arow0 + ib0 + h * 16 + g * 4));
        aN[1][h] = __builtin_nontemporal_load((const f32x4*)(arow1 + ib0 + h * 16 + g * 4));
    }

    for (int it = 0; it < ntile; ++it) {
        const int ib = ib0 + it * 32;
        short8 kC[2][4];
        f32x4 aC[2][2];
#pragma unroll
        for (int h = 0; h < 2; ++h) {
#pragma unroll
            for (int cs = 0; cs < 4; ++cs) kC[h][cs] = kN[h][cs];
            aC[0][h] = aN[0][h]; aC[1][h] = aN[1][h];
        }
        if (it + 1 < ntile) {
            const int ibn = ib + 32;
#pragma unroll
            for (int h = 0; h < 2; ++h) {
                const unsigned short* kr = Kb + (size_t)(ibn + h * 16 + q) * 128 + g * 8;
#pragma unroll
                for (int cs = 0; cs < 4; ++cs) kN[h][cs] = *(const short8*)(kr + cs * 32);
                aN[0][h] = __builtin_nontemporal_load((const f32x4*)(arow0 + ibn + h * 16 + g * 4));
                aN[1][h] = __builtin_nontemporal_load((const f32x4*)(arow1 + ibn + h * 16 + g * 4));
            }
        }

#pragma unroll
        for (int h = 0; h < 2; ++h) {
            floatx4 s0 = {0.f,0.f,0.f,0.f}, s1 = {0.f,0.f,0.f,0.f};
#pragma unroll
            for (int cs = 0; cs < 4; ++cs) {
                s0 = __builtin_amdgcn_mfma_f32_16x16x32_bf16(kC[h][cs], qf[0][cs], s0, 0, 0, 0);
                s1 = __builtin_amdgcn_mfma_f32_16x16x32_bf16(kC[h][cs], qf[1][cs], s1, 0, 0, 0);
            }
            f32x4 a0 = aC[0][h], a1 = aC[1][h];
            float p00 = __expf(s0[0] * rsd * a0[0]);
            float p01 = __expf(s0[1] * rsd * a0[1]);
            float p02 = __expf(s0[2] * rsd * a0[2]);
            float p03 = __expf(s0[3] * rsd * a0[3]);
            float p10 = __expf(s1[0] * rsd * a1[0]);
            float p11 = __expf(s1[1] * rsd * a1[1]);
            float p12 = __expf(s1[2] * rsd * a1[2]);
            float p13 = __expf(s1[3] * rsd * a1[3]);
            l0 += (p00 + p01) + (p02 + p03);
            l1 += (p10 + p11) + (p12 + p13);
            *(uint2*)&Pw[q * PST + h * 16 + g * 4]        = make_uint2(packbf2(p00, p01), packbf2(p02, p03));
            *(uint2*)&Pw[(16 + q) * PST + h * 16 + g * 4] = make_uint2(packbf2(p10, p11), packbf2(p12, p13));
        }
        short8 pf0 = *(const short8*)&Pw[q * PST + g * 8];
        short8 pf1 = *(const short8*)&Pw[(16 + q) * PST + g * 8];
#pragma unroll
        for (int ct = 0; ct < 8; ++ct) {
            short8 vf = *(const short8*)(Vbp + (size_t)(ct * 16 + q) * N + ib + g * 8);
            macc[ct][0] = __builtin_amdgcn_mfma_f32_16x16x32_bf16(vf, pf0, macc[ct][0], 0, 0, 0);
            macc[ct][1] = __builtin_amdgcn_mfma_f32_16x16x32_bf16(vf, pf1, macc[ct][1], 0, 0, 0);
        }
    }

    // partial denominator per o
    l0 += __shfl_xor(l0, 16); l0 += __shfl_xor(l0, 32);
    l1 += __shfl_xor(l1, 16); l1 += __shfl_xor(l1, 32);
    if (lane < 16) { l_s[w][q] = l0; l_s[w][16 + q] = l1; }
    __syncthreads();
    if (t < 32) {
        float s = 0.f;
#pragma unroll
        for (int w2 = 0; w2 < 8; ++w2) s += l_s[w2][t];
        pl[(size_t)(split * bs + b) * N + obase + t] = s;
    }
    // chunked 8-way combine -> unnormalized partial message
    float* pbase = pmsg + (size_t)(split * bs + b) * 128 * N;
#pragma unroll
    for (int ct = 0; ct < 8; ++ct) {
#pragma unroll
        for (int ot = 0; ot < 2; ++ot)
#pragma unroll
            for (int r = 0; r < 4; ++r)
                comb_s[w][(g * 4 + r) * 33 + 16 * ot + q] = macc[ct][ot][r];
        __syncthreads();
        {
            int c = t >> 5, o = t & 31;
            float s = 0.f;
#pragma unroll
            for (int w2 = 0; w2 < 8; ++w2) s += comb_s[w2][c * 33 + o];
            pbase[(size_t)(ct * 16 + c) * N + obase + o] = s;
        }
        __syncthreads();
    }
}

// ---------------- Kernel 3: fused merge + MLP + residual ----------------
__global__ __launch_bounds__(256) void mlp_kernel(
    const float* __restrict__ pmsg, const float* __restrict__ pl,
    const float* __restrict__ feat,
    const float* __restrict__ W1, const float* __restrict__ b1,
    const float* __restrict__ g1, const float* __restrict__ be1,
    const float* __restrict__ m1, const float* __restrict__ v1,
    const float* __restrict__ W2, const float* __restrict__ b2,
    const float* __restrict__ g2, const float* __restrict__ be2,
    const float* __restrict__ m2, const float* __restrict__ v2,
    const float* __restrict__ W3, const float* __restrict__ b3,
    float* __restrict__ out, int N, int bs)
{
    const int b = blockIdx.y;
    const int nb = blockIdx.x * 32;
    const int t = threadIdx.x;
    const int n_l = t & 31, og = t >> 5;   // 8 groups
    const float EPS = 1e-5f;

    __shared__ float h1_s[64][32];
    __shared__ float h2_s[64][32];
    __shared__ float linv_s[32];

    const float* p0 = pmsg + (size_t)b * 128 * N + nb;
    const float* p1 = pmsg + (size_t)(bs + b) * 128 * N + nb;
    if (t < 32)
        linv_s[t] = 1.f / (pl[(size_t)b * N + nb + t] + pl[(size_t)(bs + b) * N + nb + t]);
    __syncthreads();

    float acc[8];
#pragma unroll
    for (int i = 0; i < 8; ++i) acc[i] = 0.f;
    for (int c4 = 0; c4 < 128; c4 += 4) {
        float f0 = (p0[(size_t)(c4 + 0) * N + n_l] + p1[(size_t)(c4 + 0) * N + n_l]) * linv_s[n_l];
        float f1 = (p0[(size_t)(c4 + 1) * N + n_l] + p1[(size_t)(c4 + 1) * N + n_l]) * linv_s[n_l];
        float f2 = (p0[(size_t)(c4 + 2) * N + n_l] + p1[(size_t)(c4 + 2) * N + n_l]) * linv_s[n_l];
        float f3 = (p0[(size_t)(c4 + 3) * N + n_l] + p1[(size_t)(c4 + 3) * N + n_l]) * linv_s[n_l];
#pragma unroll
        for (int oi = 0; oi < 8; ++oi) {
            float4 wv = *(const float4*)(W1 + (og * 8 + oi) * 128 + c4);
            acc[oi] += wv.x * f0 + wv.y * f1 + wv.z * f2 + wv.w * f3;
        }
    }
#pragma unroll
    for (int oi = 0; oi < 8; ++oi) {
        int o = og * 8 + oi;
        float inv = g1[o] / sqrtf(v1[o] + EPS);
        float val = (acc[oi] + b1[o]) * inv + (be1[o] - m1[o] * inv);
        h1_s[o][n_l] = fmaxf(val, 0.f);
    }
    __syncthreads();

    float acc2[8];
#pragma unroll
    for (int i = 0; i < 8; ++i) acc2[i] = 0.f;
    for (int c4 = 0; c4 < 64; c4 += 4) {
        float f0 = h1_s[c4 + 0][n_l], f1 = h1_s[c4 + 1][n_l];
        float f2 = h1_s[c4 + 2][n_l], f3 = h1_s[c4 + 3][n_l];
#pragma unroll
        for (int oi = 0; oi < 8; ++oi) {
            float4 wv = *(const float4*)(W2 + (og * 8 + oi) * 64 + c4);
            acc2[oi] += wv.x * f0 + wv.y * f1 + wv.z * f2 + wv.w * f3;
        }
    }
#pragma unroll
    for (int oi = 0; oi < 8; ++oi) {
        int o = og * 8 + oi;
        float inv = g2[o] / sqrtf(v2[o] + EPS);
        float val = (acc2[oi] + b2[o]) * inv + (be2[o] - m2[o] * inv);
        h2_s[o][n_l] = fmaxf(val, 0.f);
    }
    __syncthreads();

    float acc3[16];
#pragma unroll
    for (int i = 0; i < 16; ++i) acc3[i] = 0.f;
    for (int c4 = 0; c4 < 64; c4 += 4) {
        float f0 = h2_s[c4 + 0][n_l], f1 = h2_s[c4 + 1][n_l];
        float f2 = h2_s[c4 + 2][n_l], f3 = h2_s[c4 + 3][n_l];
#pragma unroll
        for (int oi = 0; oi < 16; ++oi) {
            float4 wv = *(const float4*)(W3 + (og * 16 + oi) * 64 + c4);
            acc3[oi] += wv.x * f0 + wv.y * f1 + wv.z * f2 + wv.w * f3;
        }
    }
#pragma unroll
    for (int oi = 0; oi < 16; ++oi) {
        int o = og * 16 + oi;
        size_t idx = (size_t)(b * 128 + o) * N + nb + n_l;
        out[idx] = feat[idx] + acc3[oi] + b3[o];
    }
}

extern "C" void kernel_launch(void* const* d_in, const int* in_sizes, int n_in,
                              void* d_out, int out_size, void* d_ws, size_t ws_size,
                              hipStream_t stream)
{
    const float* feat = (const float*)d_in[0];
    const float* att  = (const float*)d_in[1];
    const float* Wq = (const float*)d_in[2];  const float* bq = (const float*)d_in[3];
    const float* Wk = (const float*)d_in[4];  const float* bk = (const float*)d_in[5];
    const float* Wv = (const float*)d_in[6];  const float* bv = (const float*)d_in[7];
    const float* W1 = (const float*)d_in[8];  const float* b1 = (const float*)d_in[9];
    const float* g1 = (const float*)d_in[10]; const float* be1 = (const float*)d_in[11];
    const float* m1 = (const float*)d_in[12]; const float* v1 = (const float*)d_in[13];
    const float* W2 = (const float*)d_in[14]; const float* b2 = (const float*)d_in[15];
    const float* g2 = (const float*)d_in[16]; const float* be2 = (const float*)d_in[17];
    const float* m2 = (const float*)d_in[18]; const float* v2 = (const float*)d_in[19];
    const float* W3 = (const float*)d_in[20]; const float* b3 = (const float*)d_in[21];

    long long bsN = (long long)in_sizes[0] / 128;   // bs*N
    long long NN  = (long long)in_sizes[1];         // bs*N*N
    int N  = (int)(NN / bsN);
    int bs = (int)(bsN / N);

    char* ws = (char*)d_ws;
    unsigned short* Qt = (unsigned short*)ws;            // bs*N*128 bf16
    unsigned short* Kt = Qt + (size_t)bs * N * 128;      // bs*N*128 bf16
    unsigned short* Vb = Kt + (size_t)bs * N * 128;      // bs*128*N bf16
    float* pmsg = (float*)(Vb + (size_t)bs * N * 128);   // 2*bs*128*N f32 partial messages
    float* pl   = pmsg + (size_t)2 * bs * 128 * N;       // 2*bs*N f32 partial denominators

    dim3 grid1(N / 64, 2, bs);
    qkv_kernel<<<grid1, 256, 0, stream>>>(feat, Wq, bq, Wk, bk, Wv, bv, Qt, Kt, Vb, N);

    dim3 grid2(N / 32, 2, bs);
    attn_kernel<<<grid2, 512, 0, stream>>>(Qt, Kt, Vb, att, pmsg, pl, N, bs);

    dim3 grid3(N / 32, bs);
    mlp_kernel<<<grid3, 256, 0, stream>>>(pmsg, pl, feat,
        W1, b1, g1, be1, m1, v1, W2, b2, g2, be2, m2, v2, W3, b3,
        (float*)d_out, N, bs);
}

// Round 9
// 87.272 us; speedup vs baseline: 4.3728x; 1.4930x over previous
//
#include <hip/hip_runtime.h>
#include <hip/hip_bf16.h>
#include <math.h>

typedef __attribute__((ext_vector_type(8))) short short8;   // bf16x8 MFMA frag
typedef __attribute__((ext_vector_type(4))) float floatx4;  // f32x4 MFMA acc
typedef float __attribute__((ext_vector_type(4))) f32x4;

static __device__ __forceinline__ unsigned short f2bf(float x) {
    union { float f; unsigned u; } v; v.f = x;
    unsigned r = v.u + 0x7FFFu + ((v.u >> 16) & 1u);
    return (unsigned short)(r >> 16);
}
static __device__ __forceinline__ unsigned packbf2(float a, float b) {
    return (unsigned)f2bf(a) | ((unsigned)f2bf(b) << 16);
}

// ---------------- Kernel 1: QKV projections via MFMA ----------------
__global__ __launch_bounds__(256) void qkv_kernel(
    const float* __restrict__ feat,
    const float* __restrict__ Wq, const float* __restrict__ bq,
    const float* __restrict__ Wk, const float* __restrict__ bk,
    const float* __restrict__ Wv, const float* __restrict__ bv,
    unsigned short* __restrict__ Qt, unsigned short* __restrict__ Kt,
    unsigned short* __restrict__ Vb, int N)
{
    const int n0 = blockIdx.x * 64;
    const int oh = blockIdx.y;           // o-half (64 o's)
    const int b  = blockIdx.z;
    const int t = threadIdx.x;
    const int w = t >> 6, lane = t & 63, g = lane >> 4, q = lane & 15;

    __shared__ __align__(16) unsigned ft[64 * 64];   // [n][c2 swz]
    __shared__ __align__(16) unsigned wl[64 * 64];   // [o_loc][c2 swz]

    const float* fb = feat + (size_t)b * 128 * N + n0;
    {
        int n = lane;
        int swz = (n & 7) << 2;
#pragma unroll
        for (int iter = 0; iter < 16; ++iter) {
            int c2 = iter * 4 + w;
            float x0 = fb[(size_t)(2 * c2) * N + n];
            float x1 = fb[(size_t)(2 * c2 + 1) * N + n];
            ft[n * 64 + (c2 ^ swz)] = packbf2(x0, x1);
        }
    }
    __syncthreads();

    short8 af[4];
    {
        int nl = w * 16 + q;
        const unsigned* base = ft + nl * 64;
        int swz = (nl & 7) << 2;
#pragma unroll
        for (int cs = 0; cs < 4; ++cs)
            af[cs] = *(const short8*)(base + ((cs * 16 + g * 4) ^ swz));
    }

    for (int p = 0; p < 3; ++p) {
        const float* W    = p == 0 ? Wq : (p == 1 ? Wk : Wv);
        const float* bias = p == 0 ? bq : (p == 1 ? bk : bv);
        const float* Wsrc = W + (size_t)oh * 64 * 128;
        __syncthreads();
        {
            int c2 = lane;
#pragma unroll
            for (int iter = 0; iter < 16; ++iter) {
                int ol = iter * 4 + w;
                float2 v = *(const float2*)(Wsrc + ol * 128 + c2 * 2);
                wl[ol * 64 + (c2 ^ ((ol & 7) << 2))] = packbf2(v.x, v.y);
            }
        }
        __syncthreads();

#pragma unroll
        for (int ot = 0; ot < 4; ++ot) {
            short8 wf[4];
            {
                const unsigned* basep = wl + (ot * 16 + q) * 64;
                int swz = (q & 7) << 2;
#pragma unroll
                for (int cs = 0; cs < 4; ++cs)
                    wf[cs] = *(const short8*)(basep + ((cs * 16 + g * 4) ^ swz));
            }
            floatx4 acc = {0.f, 0.f, 0.f, 0.f};
            if (p < 2) {
#pragma unroll
                for (int cs = 0; cs < 4; ++cs)
                    acc = __builtin_amdgcn_mfma_f32_16x16x32_bf16(af[cs], wf[cs], acc, 0, 0, 0);
                int o = oh * 64 + ot * 16 + q;
                float bo = bias[o];
                unsigned short* T = (p == 0 ? Qt : Kt) + (size_t)b * N * 128;
#pragma unroll
                for (int rr = 0; rr < 4; ++rr) {
                    int n = n0 + w * 16 + g * 4 + rr;
                    T[(size_t)n * 128 + o] = f2bf(acc[rr] + bo);
                }
            } else {
#pragma unroll
                for (int cs = 0; cs < 4; ++cs)
                    acc = __builtin_amdgcn_mfma_f32_16x16x32_bf16(wf[cs], af[cs], acc, 0, 0, 0);
                int n = n0 + w * 16 + q;
#pragma unroll
                for (int rr = 0; rr < 4; ++rr) {
                    int o = oh * 64 + ot * 16 + g * 4 + rr;
                    Vb[((size_t)b * 128 + o) * N + n] = f2bf(acc[rr] + bias[o]);
                }
            }
        }
    }
}

// ---------------- Kernel 2: block-cooperative flash attention ----------------
// Block: 64 o's, i-range N/4 (split-i NS=4), 8 waves. Per 32-i step: K/V/att
// staged double-buffered via global_load_lds (pre-swizzled global source,
// XOR-swizzled LDS reads). Wave (isub=w>>2, osub=w&3): QK tile 16i x 16o,
// PV tiles c = isub*64 + cc*16. Outputs are wave-exclusive -> direct stores.
#define NS 4
__global__ __launch_bounds__(512) void attn_kernel(
    const unsigned short* __restrict__ Qt, const unsigned short* __restrict__ Kt,
    const unsigned short* __restrict__ Vb, const float* __restrict__ att,
    float* __restrict__ pmsg, float* __restrict__ pl, int N, int bs)
{
    const int b = blockIdx.z;
    const int split = blockIdx.y;
    const int obase = blockIdx.x * 64;
    const int t = threadIdx.x;
    const int w = t >> 6, lane = t & 63, g = lane >> 4, q = lane & 15;
    const int osub = w & 3, isub = w >> 2;

    __shared__ __align__(16) unsigned short K_l[2][32 * 128];  // 16 KB, [i][c] swz
    __shared__ __align__(16) unsigned short V_l[2][128 * 32];  // 16 KB, [c][i] swz
    __shared__ __align__(16) float att_l[2][64 * 32];          // 16 KB, [o][i] swz
    __shared__ __align__(16) unsigned short P_l[64 * 32];      // 4 KB,  [o][i] swz
    __shared__ float l_s[8][16];

    const unsigned short* Qb  = Qt + (size_t)b * N * 128;
    const unsigned short* Kb  = Kt + (size_t)b * N * 128;
    const unsigned short* Vbp = Vb + (size_t)b * 128 * N;
    const float* attb = att + (size_t)b * N * N;

    // Q B-frags: o = obase + osub*16 + q
    short8 qf[4];
#pragma unroll
    for (int cs = 0; cs < 4; ++cs)
        qf[cs] = *(const short8*)(Qb + (size_t)(obase + osub * 16 + q) * 128 + cs * 32 + g * 8);

    floatx4 macc[4];
#pragma unroll
    for (int cc = 0; cc < 4; ++cc) macc[cc] = (floatx4){0.f, 0.f, 0.f, 0.f};
    float l0 = 0.f;
    const float rsd = 0.08838834764831845f;   // 1/sqrt(128)

    const int i0 = split * (N >> 2);
    const int nsteps = (N >> 2) >> 5;

    // staging lane decomposition (content pre-swizzled via global chunk index)
    const int kr = (w << 2) + (lane >> 4);           // K tile row (i) 0..31
    const int kj = (lane & 15) ^ (kr & 7);           // global 16B chunk (of 16)
    const int vc = (w << 4) + (lane >> 2);           // V tile row (c) 0..127
    const int vj = (lane & 3) ^ ((vc >> 1) & 3);     // global chunk (of 4)
    const int ao = (w << 3) + (lane >> 3);           // att tile row (o) 0..63
    const int aj = (lane & 7) ^ (ao & 7);            // global chunk (of 8)

    // compute-side constants
    const int lr = isub * 16 + q;                    // QK A-frag K-row
    const int ol = osub * 16 + q;                    // o row
    const int osw = (ol >> 1) & 3;                   // P swizzle key
    const int pwj = ((isub * 2 + (g >> 1)) ^ osw) << 4;   // P write 16B slot
    const int prj = (g ^ osw) << 4;                       // P read 16B slot

    int cur = 0;
    {   // prologue: stage step 0 into buf 0
        const int ib = i0;
        __builtin_amdgcn_global_load_lds(
            (const void*)(Kb + (size_t)(ib + kr) * 128 + (kj << 3)),
            (void*)((char*)&K_l[0][0] + w * 1024 + lane * 16), 16, 0, 0);
        __builtin_amdgcn_global_load_lds(
            (const void*)(Vbp + (size_t)vc * N + ib + (vj << 3)),
            (void*)((char*)&V_l[0][0] + w * 1024 + lane * 16), 16, 0, 0);
        __builtin_amdgcn_global_load_lds(
            (const void*)(attb + (size_t)(obase + ao) * N + ib + (aj << 2)),
            (void*)((char*)&att_l[0][0] + w * 1024 + lane * 16), 16, 0, 0);
    }
    __syncthreads();

    for (int st = 0; st < nsteps; ++st) {
        if (st + 1 < nsteps) {   // stage next step into the other buffer
            const int ib = i0 + (st + 1) * 32;
            const int nb = cur ^ 1;
            __builtin_amdgcn_global_load_lds(
                (const void*)(Kb + (size_t)(ib + kr) * 128 + (kj << 3)),
                (void*)((char*)&K_l[nb][0] + w * 1024 + lane * 16), 16, 0, 0);
            __builtin_amdgcn_global_load_lds(
                (const void*)(Vbp + (size_t)vc * N + ib + (vj << 3)),
                (void*)((char*)&V_l[nb][0] + w * 1024 + lane * 16), 16, 0, 0);
            __builtin_amdgcn_global_load_lds(
                (const void*)(attb + (size_t)(obase + ao) * N + ib + (aj << 2)),
                (void*)((char*)&att_l[nb][0] + w * 1024 + lane * 16), 16, 0, 0);
        }

        // ---- QK phase: S^T tile (16 i x 16 o) for this wave ----
        floatx4 s = {0.f, 0.f, 0.f, 0.f};
        {
            const unsigned short* Kl = &K_l[cur][0];
#pragma unroll
            for (int cs = 0; cs < 4; ++cs) {
                short8 kf = *(const short8*)(Kl + lr * 128 + ((((cs << 2) + g) ^ (lr & 7)) << 3));
                s = __builtin_amdgcn_mfma_f32_16x16x32_bf16(kf, qf[cs], s, 0, 0, 0);
            }
        }
        f32x4 av = *(const f32x4*)(&att_l[cur][0] + ol * 32 + ((((isub << 2) + g) ^ (ol & 7)) << 2));
        float p0 = __expf(s[0] * rsd * av[0]);
        float p1 = __expf(s[1] * rsd * av[1]);
        float p2 = __expf(s[2] * rsd * av[2]);
        float p3 = __expf(s[3] * rsd * av[3]);
        l0 += (p0 + p1) + (p2 + p3);
        *(uint2*)((char*)&P_l[0] + ol * 64 + pwj + ((g & 1) << 3)) =
            make_uint2(packbf2(p0, p1), packbf2(p2, p3));
        __syncthreads();   // P complete (all waves)

        // ---- PV phase: c tiles isub*64 + cc*16, k = this step's 32 i ----
        {
            short8 pf = *(const short8*)((const char*)&P_l[0] + ol * 64 + prj);
            const unsigned short* Vl = &V_l[cur][0];
#pragma unroll
            for (int cc = 0; cc < 4; ++cc) {
                int c = ((isub << 2) + cc) * 16 + q;
                short8 vf = *(const short8*)(Vl + c * 32 + ((g ^ ((c >> 1) & 3)) << 3));
                macc[cc] = __builtin_amdgcn_mfma_f32_16x16x32_bf16(vf, pf, macc[cc], 0, 0, 0);
            }
        }
        __syncthreads();   // PV reads done; next staged buffer ready
        cur ^= 1;
    }

    // partial denominator: reduce over g-groups, combine isub pairs
    l0 += __shfl_xor(l0, 16);
    l0 += __shfl_xor(l0, 32);
    if (lane < 16) l_s[w][q] = l0;
    __syncthreads();
    if (t < 64)
        pl[(size_t)(split * bs + b) * N + obase + t] =
            l_s[t >> 4][t & 15] + l_s[(t >> 4) + 4][t & 15];

    // partial message: wave-exclusive (c,o) tiles -> direct stores
    float* pbase = pmsg + (size_t)(split * bs + b) * 128 * N;
    const int og = obase + osub * 16 + q;
#pragma unroll
    for (int cc = 0; cc < 4; ++cc) {
        int c = ((isub << 2) + cc) * 16 + (g << 2);
#pragma unroll
        for (int r = 0; r < 4; ++r)
            pbase[(size_t)(c + r) * N + og] = macc[cc][r];
    }
}

// ---------------- Kernel 3: fused 4-way merge + MLP + residual ----------------
__global__ __launch_bounds__(256) void mlp_kernel(
    const float* __restrict__ pmsg, const float* __restrict__ pl,
    const float* __restrict__ feat,
    const float* __restrict__ W1, const float* __restrict__ b1,
    const float* __restrict__ g1, const float* __restrict__ be1,
    const float* __restrict__ m1, const float* __restrict__ v1,
    const float* __restrict__ W2, const float* __restrict__ b2,
    const float* __restrict__ g2, const float* __restrict__ be2,
    const float* __restrict__ m2, const float* __restrict__ v2,
    const float* __restrict__ W3, const float* __restrict__ b3,
    float* __restrict__ out, int N, int bs)
{
    const int b = blockIdx.y;
    const int nb = blockIdx.x * 32;
    const int t = threadIdx.x;
    const int n_l = t & 31, og = t >> 5;   // 8 groups
    const float EPS = 1e-5f;

    __shared__ float h1_s[64][32];
    __shared__ float h2_s[64][32];
    __shared__ float linv_s[32];

    const float* p0 = pmsg + (size_t)b * 128 * N + nb;
    const float* p1 = pmsg + (size_t)(bs + b) * 128 * N + nb;
    const float* p2 = pmsg + (size_t)(2 * bs + b) * 128 * N + nb;
    const float* p3 = pmsg + (size_t)(3 * bs + b) * 128 * N + nb;
    if (t < 32) {
        float s = pl[(size_t)b * N + nb + t] + pl[(size_t)(bs + b) * N + nb + t]
                + pl[(size_t)(2 * bs + b) * N + nb + t] + pl[(size_t)(3 * bs + b) * N + nb + t];
        linv_s[t] = 1.f / s;
    }
    __syncthreads();

    float acc[8];
#pragma unroll
    for (int i = 0; i < 8; ++i) acc[i] = 0.f;
    for (int c4 = 0; c4 < 128; c4 += 4) {
        float fv[4];
#pragma unroll
        for (int k = 0; k < 4; ++k) {
            size_t idx = (size_t)(c4 + k) * N + n_l;
            fv[k] = (p0[idx] + p1[idx] + p2[idx] + p3[idx]) * linv_s[n_l];
        }
#pragma unroll
        for (int oi = 0; oi < 8; ++oi) {
            float4 wv = *(const float4*)(W1 + (og * 8 + oi) * 128 + c4);
            acc[oi] += wv.x * fv[0] + wv.y * fv[1] + wv.z * fv[2] + wv.w * fv[3];
        }
    }
#pragma unroll
    for (int oi = 0; oi < 8; ++oi) {
        int o = og * 8 + oi;
        float inv = g1[o] / sqrtf(v1[o] + EPS);
        float val = (acc[oi] + b1[o]) * inv + (be1[o] - m1[o] * inv);
        h1_s[o][n_l] = fmaxf(val, 0.f);
    }
    __syncthreads();

    float acc2[8];
#pragma unroll
    for (int i = 0; i < 8; ++i) acc2[i] = 0.f;
    for (int c4 = 0; c4 < 64; c4 += 4) {
        float f0 = h1_s[c4 + 0][n_l], f1 = h1_s[c4 + 1][n_l];
        float f2 = h1_s[c4 + 2][n_l], f3 = h1_s[c4 + 3][n_l];
#pragma unroll
        for (int oi = 0; oi < 8; ++oi) {
            float4 wv = *(const float4*)(W2 + (og * 8 + oi) * 64 + c4);
            acc2[oi] += wv.x * f0 + wv.y * f1 + wv.z * f2 + wv.w * f3;
        }
    }
#pragma unroll
    for (int oi = 0; oi < 8; ++oi) {
        int o = og * 8 + oi;
        float inv = g2[o] / sqrtf(v2[o] + EPS);
        float val = (acc2[oi] + b2[o]) * inv + (be2[o] - m2[o] * inv);
        h2_s[o][n_l] = fmaxf(val, 0.f);
    }
    __syncthreads();

    float acc3[16];
#pragma unroll
    for (int i = 0; i < 16; ++i) acc3[i] = 0.f;
    for (int c4 = 0; c4 < 64; c4 += 4) {
        float f0 = h2_s[c4 + 0][n_l], f1 = h2_s[c4 + 1][n_l];
        float f2 = h2_s[c4 + 2][n_l], f3 = h2_s[c4 + 3][n_l];
#pragma unroll
        for (int oi = 0; oi < 16; ++oi) {
            float4 wv = *(const float4*)(W3 + (og * 16 + oi) * 64 + c4);
            acc3[oi] += wv.x * f0 + wv.y * f1 + wv.z * f2 + wv.w * f3;
        }
    }
#pragma unroll
    for (int oi = 0; oi < 16; ++oi) {
        int o = og * 16 + oi;
        size_t idx = (size_t)(b * 128 + o) * N + nb + n_l;
        out[idx] = feat[idx] + acc3[oi] + b3[o];
    }
}

extern "C" void kernel_launch(void* const* d_in, const int* in_sizes, int n_in,
                              void* d_out, int out_size, void* d_ws, size_t ws_size,
                              hipStream_t stream)
{
    const float* feat = (const float*)d_in[0];
    const float* att  = (const float*)d_in[1];
    const float* Wq = (const float*)d_in[2];  const float* bq = (const float*)d_in[3];
    const float* Wk = (const float*)d_in[4];  const float* bk = (const float*)d_in[5];
    const float* Wv = (const float*)d_in[6];  const float* bv = (const float*)d_in[7];
    const float* W1 = (const float*)d_in[8];  const float* b1 = (const float*)d_in[9];
    const float* g1 = (const float*)d_in[10]; const float* be1 = (const float*)d_in[11];
    const float* m1 = (const float*)d_in[12]; const float* v1 = (const float*)d_in[13];
    const float* W2 = (const float*)d_in[14]; const float* b2 = (const float*)d_in[15];
    const float* g2 = (const float*)d_in[16]; const float* be2 = (const float*)d_in[17];
    const float* m2 = (const float*)d_in[18]; const float* v2 = (const float*)d_in[19];
    const float* W3 = (const float*)d_in[20]; const float* b3 = (const float*)d_in[21];

    long long bsN = (long long)in_sizes[0] / 128;   // bs*N
    long long NN  = (long long)in_sizes[1];         // bs*N*N
    int N  = (int)(NN / bsN);
    int bs = (int)(bsN / N);

    char* ws = (char*)d_ws;
    unsigned short* Qt = (unsigned short*)ws;            // bs*N*128 bf16
    unsigned short* Kt = Qt + (size_t)bs * N * 128;      // bs*N*128 bf16
    unsigned short* Vb = Kt + (size_t)bs * N * 128;      // bs*128*N bf16
    float* pmsg = (float*)(Vb + (size_t)bs * N * 128);   // NS*bs*128*N f32 partials
    float* pl   = pmsg + (size_t)NS * bs * 128 * N;      // NS*bs*N f32 partial denoms

    dim3 grid1(N / 64, 2, bs);
    qkv_kernel<<<grid1, 256, 0, stream>>>(feat, Wq, bq, Wk, bk, Wv, bv, Qt, Kt, Vb, N);

    dim3 grid2(N / 64, NS, bs);
    attn_kernel<<<grid2, 512, 0, stream>>>(Qt, Kt, Vb, att, pmsg, pl, N, bs);

    dim3 grid3(N / 32, bs);
    mlp_kernel<<<grid3, 256, 0, stream>>>(pmsg, pl, feat,
        W1, b1, g1, be1, m1, v1, W2, b2, g2, be2, m2, v2, W3, b3,
        (float*)d_out, N, bs);
}